// Round 6
// baseline (33.653 us; speedup 1.0000x reference)
//
#include <hip/hip_runtime.h>

constexpr int NJ = 31;
constexpr int ROWS = 16;      // batch rows per block (64 threads, 4 lanes/row)
constexpr int JF = NJ * 4;    // 124 floats per row

struct M34 {
    float r[9];  // row-major 3x3
    float t[3];
};

// RT_j = R4(q) @ T_j as 3x4 affine. offsets address is compile-time-uniform per
// unrolled j -> compiler uses scalar loads (s_load, L1/K$ resident, ~free).
__device__ __forceinline__ void make_RT(int j, float4 q, float len,
                                        const float* __restrict__ offs,
                                        float Rr[9], float Rt[3]) {
    const float w = q.x, x = q.y, y = q.z, z = q.w;
    const float two_s = 2.0f / (w * w + x * x + y * y + z * z);
    float R[9];
    R[0] = 1.0f - two_s * (y * y + z * z);
    R[1] = two_s * (x * y - z * w);
    R[2] = two_s * (x * z + y * w);
    R[3] = two_s * (x * y + z * w);
    R[4] = 1.0f - two_s * (x * x + z * z);
    R[5] = two_s * (y * z - x * w);
    R[6] = two_s * (x * z - y * w);
    R[7] = two_s * (y * z + x * w);
    R[8] = 1.0f - two_s * (x * x + y * y);

    const float4* O4 = reinterpret_cast<const float4*>(offs) + (size_t)j * 4;
    const float4 o0 = O4[0], o1 = O4[1], o2 = O4[2];  // rows 0..2 of 4x4
    const float O[12] = {o0.x, o0.y, o0.z, o1.x, o1.y, o1.z, o2.x, o2.y, o2.z,
                         o0.w * len, o1.w * len, o2.w * len};
#pragma unroll
    for (int r = 0; r < 3; ++r) {
#pragma unroll
        for (int c = 0; c < 3; ++c) {
            Rr[r * 3 + c] = R[r * 3 + 0] * O[0 + c] +
                            R[r * 3 + 1] * O[3 + c] +
                            R[r * 3 + 2] * O[6 + c];
        }
        Rt[r] = R[r * 3 + 0] * O[9] + R[r * 3 + 1] * O[10] + R[r * 3 + 2] * O[11];
    }
}

__device__ __forceinline__ M34 compose(const M34& P, const float Rr[9],
                                       const float Rt[3]) {
    M34 C;
#pragma unroll
    for (int r = 0; r < 3; ++r) {
#pragma unroll
        for (int c = 0; c < 3; ++c) {
            C.r[r * 3 + c] = P.r[r * 3 + 0] * Rr[0 * 3 + c] +
                             P.r[r * 3 + 1] * Rr[1 * 3 + c] +
                             P.r[r * 3 + 2] * Rr[2 * 3 + c];
        }
        C.t[r] = P.r[r * 3 + 0] * Rt[0] + P.r[r * 3 + 1] * Rt[1] +
                 P.r[r * 3 + 2] * Rt[2] + P.t[r];
    }
    return C;
}

__global__ __launch_bounds__(64, 4) void fk_layer_kernel(
    const float* __restrict__ root_position,  // (B,3)
    const float* __restrict__ joint,          // (B, NJ*4)
    const float* __restrict__ fbl,            // (B, NJ)
    const float* __restrict__ offsets,        // (NJ,4,4)
    float* __restrict__ out) {                // (B, NJ, 4)
    __shared__ float so[ROWS * JF];  // 7936 B output tile only

    const int lane = threadIdx.x;
    const int r = lane >> 2;        // row within tile
    const int c = lane & 3;         // chain lane
    const int cc = c < 2 ? c : 2;   // c==3 duplicates c==2 (stores masked)
    const int rowBase = blockIdx.x * ROWS;
    const size_t b = (size_t)(rowBase + r);

    // ---- issue ALL global loads up front (register-resident, max MLP) ----
    const float4* jq = reinterpret_cast<const float4*>(joint + b * JF);
    float4 q0 = jq[0];
    float4 qa[5], qb[5];
#pragma unroll
    for (int s = 0; s < 5; ++s) qa[s] = jq[1 + 5 * cc + s];
#pragma unroll
    for (int s = 0; s < 5; ++s) qb[s] = jq[16 + 5 * cc + s];

    const float* fr = fbl + b * NJ;
    const float f0 = fr[0];
    float fa[5], fb_[5];
#pragma unroll
    for (int s = 0; s < 5; ++s) fa[s] = fr[1 + 5 * cc + s];
#pragma unroll
    for (int s = 0; s < 5; ++s) fb_[s] = fr[16 + 5 * cc + s];

    const float rx = root_position[b * 3 + 0] * 100.0f;
    const float ry = root_position[b * 3 + 1] * 100.0f;
    const float rz = root_position[b * 3 + 2] * 100.0f;

    float* srow = so + r * JF;

    // ---- M0 (all 4 lanes redundantly) ----
    M34 M0;
    {
        float Rr[9], Rt[3];
        make_RT(0, q0, f0, offsets, Rr, Rt);
#pragma unroll
        for (int i = 0; i < 9; ++i) M0.r[i] = Rr[i];
        M0.t[0] = Rt[0] + rx;
        M0.t[1] = Rt[1] + ry;
        M0.t[2] = Rt[2] + rz;
        if (c == 0)
            *reinterpret_cast<float4*>(&srow[0]) =
                make_float4(M0.t[0], M0.t[1], M0.t[2], 1.0f);
    }

    // ---- stage A: chains {1-5},{6-10},{11-15} from M0 ----
    M34 cur = M0, M13 = M0;
    {
        const int jb = 1 + 5 * cc;
#pragma unroll
        for (int s = 0; s < 5; ++s) {
            const int j = jb + s;
            float Rr[9], Rt[3];
            make_RT(j, qa[s], fa[s], offsets, Rr, Rt);
            cur = compose(cur, Rr, Rt);
            if (c < 3)
                *reinterpret_cast<float4*>(&srow[j * 4]) =
                    make_float4(cur.t[0], cur.t[1], cur.t[2], 1.0f);
            if (s == 2) M13 = cur;  // j==13 on the c==2/3 lanes
        }
    }

    // ---- broadcast M13 from lane (group|2) ----
    const int src = (lane & ~3) | 2;
#pragma unroll
    for (int i = 0; i < 9; ++i) M13.r[i] = __shfl(M13.r[i], src, 64);
#pragma unroll
    for (int i = 0; i < 3; ++i) M13.t[i] = __shfl(M13.t[i], src, 64);

    // ---- stage B: chains {16-20},{21-25},{26-30} from M13 ----
    cur = M13;
    {
        const int jb = 16 + 5 * cc;
#pragma unroll
        for (int s = 0; s < 5; ++s) {
            const int j = jb + s;
            float Rr[9], Rt[3];
            make_RT(j, qb[s], fb_[s], offsets, Rr, Rt);
            cur = compose(cur, Rr, Rt);
            if (c < 3)
                *reinterpret_cast<float4*>(&srow[j * 4]) =
                    make_float4(cur.t[0], cur.t[1], cur.t[2], 1.0f);
        }
    }

    __syncthreads();  // LDS writes visible (single wave: ~free)

    // ---- coalesced store: 496 float4 (7936 B contiguous) ----
    const float4* s4 = reinterpret_cast<const float4*>(so);
    float4* gout = reinterpret_cast<float4*>(out + (size_t)rowBase * JF);
#pragma unroll
    for (int ch = 0; ch < 8; ++ch) {
        const int idx = ch * 64 + lane;
        if (idx < ROWS * NJ) gout[idx] = s4[idx];
    }
}

extern "C" void kernel_launch(void* const* d_in, const int* in_sizes, int n_in,
                              void* d_out, int out_size, void* d_ws, size_t ws_size,
                              hipStream_t stream) {
    const float* root = (const float*)d_in[0];
    const float* joint = (const float*)d_in[1];
    const float* fblp = (const float*)d_in[2];
    const float* offs = (const float*)d_in[3];
    float* out = (float*)d_out;

    const int B = in_sizes[0] / 3;  // 131072, multiple of ROWS
    fk_layer_kernel<<<B / ROWS, 64, 0, stream>>>(root, joint, fblp, offs, out);
}